// Round 9
// baseline (3015.758 us; speedup 1.0000x reference)
//
#include <hip/hip_runtime.h>

#define T_STEPS 512
#define BATCH   256

typedef _Float16 f16;
typedef unsigned long long u64;
typedef __attribute__((ext_vector_type(8))) _Float16 f16x8;
typedef __attribute__((ext_vector_type(4))) _Float16 f16x4;
typedef __attribute__((ext_vector_type(4))) float    f32x4;

#define L2E 1.44269504088896340736f

__device__ __forceinline__ float rcp_f(float x)  { return __builtin_amdgcn_rcpf(x); }
__device__ __forceinline__ float exp2_f(float x) { return __builtin_amdgcn_exp2f(x); }

// tanh in exp2 domain: tanh(x) = 1 - 2/(exp2(2*log2e*x)+1)
__device__ __forceinline__ float tanh_n(float x) {
    return fmaf(-2.0f, rcp_f(1.0f + exp2_f(2.0f * L2E * x)), 1.0f);
}
// tanh on 4 packed f16 (bottleneck tanh, applied on L2's panel store)
__device__ __forceinline__ u64 tanh4_f16(u64 v) {
    f16x4 h = __builtin_bit_cast(f16x4, v);
    f16x4 r;
#pragma unroll
    for (int i = 0; i < 4; ++i) r[i] = (f16)tanh_n((float)h[i]);
    return __builtin_bit_cast(u64, r);
}

// Per-step barrier: LDS visibility only (global ops NOT drained).
__device__ __forceinline__ void barrier_lgkm() {
    asm volatile("s_waitcnt lgkmcnt(0)\n\ts_barrier" ::: "memory");
}
// Full drain barrier (pre/epilogue only).
__device__ __forceinline__ void barrier_drain() {
    asm volatile("s_waitcnt vmcnt(0) lgkmcnt(0)\n\ts_barrier" ::: "memory");
}
// Counted drain barrier: wait until <= K vmem ops outstanding. The K newest
// ops are this step's prefetch loads (issued AFTER all stores -> in-order
// vmcnt retirement guarantees every store is retired), so panel stores are
// globally visible without waiting on the fresh sc1 loads.
template <int K>
__device__ __forceinline__ void barrier_drain_k() {
    if constexpr (K == 1)
        asm volatile("s_waitcnt vmcnt(1) lgkmcnt(0)\n\ts_barrier" ::: "memory");
    else if constexpr (K == 2)
        asm volatile("s_waitcnt vmcnt(2) lgkmcnt(0)\n\ts_barrier" ::: "memory");
    else if constexpr (K == 4)
        asm volatile("s_waitcnt vmcnt(4) lgkmcnt(0)\n\ts_barrier" ::: "memory");
    else
        asm volatile("s_waitcnt vmcnt(0) lgkmcnt(0)\n\ts_barrier" ::: "memory");
}

// Agent-scope relaxed atomics -> sc1 ops, coherent at L3 across XCDs.
__device__ __forceinline__ int  flag_load(const int* p) {
    return __hip_atomic_load(p, __ATOMIC_RELAXED, __HIP_MEMORY_SCOPE_AGENT);
}
__device__ __forceinline__ void flag_store(int* p, int v) {
    __hip_atomic_store(p, v, __ATOMIC_RELAXED, __HIP_MEMORY_SCOPE_AGENT);
}
__device__ __forceinline__ u64  panel_load(const u64* p) {
    return __hip_atomic_load(p, __ATOMIC_RELAXED, __HIP_MEMORY_SCOPE_AGENT);
}
__device__ __forceinline__ void panel_store(u64* p, u64 v) {
    __hip_atomic_store(p, v, __ATOMIC_RELAXED, __HIP_MEMORY_SCOPE_AGENT);
}

// One LSTM layer over one 16-batch group (NT = 4H threads). MFMA structure
// verified rounds 2-6 (prior session). Weights/biases scaled by log2e (gates
// i,f,o) and 2*log2e (gate g) at load time; cell state kept in the 2*log2e
// domain; merged-rcp gate forms (8 trans/row, verified identical absmax).
//
// R7 (kept): 2-step-deep register prefetch; counted vmcnt drain. R8: groups
// packed 2-4 per block so active CUs run 16 waves (4/SIMD). R9 FIX: launch
// bounds WITHOUT a min-occupancy arg — R8's (1024,4) capped VGPR at 64 and
// spilled the weight registers to scratch (VGPR 120->64, WRITE +11MB, 5.3x
// slower). Plain (1024) caps at 128 >= the 120 this kernel needs.
template <int IN_DIM, int H, bool IN_F32, bool OUT_PANEL, bool OUT_TANH>
__device__ __forceinline__ void lstm_layer_dev(
    char* sm,
    const void* __restrict__ xv,       // IN_F32 ? f32 [T,B,IN] : f16 [T,B,IN]
    const int* in_flag,                // upstream flag (unused if IN_F32)
    int* out_flag,                     // our flag (unused if !OUT_PANEL)
    const float* __restrict__ w_ih, const float* __restrict__ w_hh,
    const float* __restrict__ b_ih, const float* __restrict__ b_hh,
    void* __restrict__ outv,           // OUT_PANEL ? f16 [T,B,H] : f32 [T,B,H]
    int group, int ltid)
{
    constexpr int KTX = IN_DIM / 32, KTH = H / 32, KT = KTX + KTH;
    constexpr int XP = IN_DIM + 8, HP = H + 8, NT = 4 * H;

    f16 (*xs)[16][XP] = (f16(*)[16][XP])sm;                       // [2][16][XP]
    f16 (*hs)[16][HP] = (f16(*)[16][HP])(sm + 2 * 16 * XP * 2);   // [2][16][HP]

    const int wave = ltid >> 6, lane = ltid & 63;
    const int col = lane & 15, q = lane >> 4;
    const int bblk = group * 16;
    const int u = wave * 16 + col;

    // ---- one-time: B-fragments (weights, log2e-scaled) -> registers ----
    f16x8 bw[4][KT];
#pragma unroll
    for (int g = 0; g < 4; ++g) {
        const float sc = (g == 2) ? 2.0f * L2E : L2E;
        const int row = g * H + u;
#pragma unroll
        for (int kt = 0; kt < KTX; ++kt) {
            const float* p = w_ih + (size_t)row * IN_DIM + kt * 32 + q * 8;
            f16x8 v;
#pragma unroll
            for (int j = 0; j < 8; ++j) v[j] = (f16)(p[j] * sc);
            bw[g][kt] = v;
        }
#pragma unroll
        for (int kt = 0; kt < KTH; ++kt) {
            const float* p = w_hh + (size_t)row * H + kt * 32 + q * 8;
            f16x8 v;
#pragma unroll
            for (int j = 0; j < 8; ++j) v[j] = (f16)(p[j] * sc);
            bw[g][KTX + kt] = v;
        }
    }
    float bias[4];
#pragma unroll
    for (int g = 0; g < 4; ++g)
        bias[g] = (b_ih[g * H + u] + b_hh[g * H + u]) * ((g == 2) ? 2.0f * L2E : L2E);
    float cst[4] = {0.f, 0.f, 0.f, 0.f};   // cell state, 2*log2e domain

    // ---- input staging: 16B chunks (4 f32 or 8 f16) ----
    constexpr int ELD = IN_F32 ? 4 : 8;
    constexpr int EPR = IN_DIM / ELD;
    constexpr int NCH = 16 * EPR;
    constexpr int CPT = (NCH + NT - 1) / NT;
    constexpr int NLOAD = IN_F32 ? CPT : 2 * CPT;   // load instrs per step
    constexpr long XADVB = (long)BATCH * IN_DIM * (IN_F32 ? 4 : 2);
    bool sv[CPT]; const char* sgp[CPT]; f16* slp[CPT];
    constexpr int LDSD = 16 * XP;          // f16 elems between xs buffers
#pragma unroll
    for (int k = 0; k < CPT; ++k) {
        const int cc = ltid + k * NT;
        sv[k] = (cc < NCH);
        const int r_ = (cc < NCH ? cc : 0) / EPR;
        const int o_ = (cc < NCH ? cc : 0) % EPR;
        sgp[k] = (const char*)xv + ((size_t)(bblk + r_) * IN_DIM + o_ * ELD) * (IN_F32 ? 4 : 2);
        slp[k] = &xs[0][r_][o_ * ELD];
    }

    // ---- output setup ----
    constexpr int OEPR = H / 4;            // u64 chunks per row; NT == 16*OEPR
    u64* opg = nullptr;
    f16* olds = nullptr;
    float* outp_f32 = nullptr;
    if constexpr (OUT_PANEL) {
        const int orow = ltid / OEPR, ooff = ltid % OEPR;
        opg  = (u64*)((f16*)outv + (size_t)(bblk + orow) * H) + ooff;
        olds = &hs[0][orow][ooff * 4];
    } else {
        outp_f32 = (float*)outv + ((size_t)bblk + 4 * q) * H + u;
    }
    constexpr int HLDSD = 16 * HP;

    // ---- pre-loop: zero h(0); wait upstream; stage x(0); issue x(1) ----
    for (int i = ltid; i < 16 * HP; i += NT) hs[0][i / HP][i % HP] = (f16)0.f;
    int seen = 0;
    if constexpr (!IN_F32) {
        do { seen = flag_load(in_flag); } while (seen < 1);
    }
#pragma unroll
    for (int k = 0; k < CPT; ++k) {
        if (sv[k]) {
            if constexpr (IN_F32) {
                const f32x4 v = *reinterpret_cast<const f32x4*>(sgp[k]);
                f16x4 h4;
                h4[0] = (f16)v[0]; h4[1] = (f16)v[1]; h4[2] = (f16)v[2]; h4[3] = (f16)v[3];
                *reinterpret_cast<f16x4*>(slp[k]) = h4;
            } else {
                u64 a = panel_load((const u64*)sgp[k]);
                u64 b = panel_load((const u64*)sgp[k] + 1);
                u64 pk[2] = {a, b};
                *reinterpret_cast<f16x8*>(slp[k]) = *reinterpret_cast<const f16x8*>(pk);
            }
            sgp[k] += XADVB;
        }
    }
    // issue x(1) into the ODD reg set (consumed at step 0's commit)
    f32x4 xr32O[CPT], xr32E[CPT];
    u64 xr16O[CPT][2], xr16E[CPT][2];
    if constexpr (!IN_F32) {
        if (seen < 2) { do { seen = flag_load(in_flag); } while (seen < 2); }
    }
#pragma unroll
    for (int k = 0; k < CPT; ++k) {
        if (sv[k]) {
            if constexpr (IN_F32) {
                xr32O[k] = *reinterpret_cast<const f32x4*>(sgp[k]);
            } else {
                xr16O[k][0] = panel_load((const u64*)sgp[k]);
                xr16O[k][1] = panel_load((const u64*)sgp[k] + 1);
            }
            sgp[k] += XADVB;
        }
    }
    barrier_lgkm();   // x(1) loads stay in flight across the barrier

    float hold[4] = {0.f, 0.f, 0.f, 0.f};

    // ---- one step; pbv/dodrain/dopub are literal at each call site.
    //      c* holds x(t+1) (loaded at t-1); i* receives x(t+2). ----
    auto step = [&](int t, int pbv, bool dodrain, bool dopub,
                    f32x4 (&c32)[CPT], f32x4 (&i32)[CPT],
                    u64 (&c16)[CPT][2], u64 (&i16)[CPT][2]) {
        if constexpr (OUT_PANEL) {
            if (dopub && t >= 4 && ltid == 0) flag_store(out_flag, t - 1);
        }

        // (1) write step t-1's output FIRST (h(t-1) sits in hs[pbv]) so the
        //     counted drain covers all stores without touching fresh loads
        if (t >= 1) {
            if constexpr (OUT_PANEL) {
                u64 v = *reinterpret_cast<const u64*>(olds + pbv * HLDSD);
                if constexpr (OUT_TANH) v = tanh4_f16(v);
                panel_store(opg, v);
                opg += (size_t)BATCH * H / 4;
            } else {
#pragma unroll
                for (int r = 0; r < 4; ++r) outp_f32[r * H] = hold[r];
                outp_f32 += (size_t)BATCH * H;
            }
        }

        // (2) issue prefetch of x(t+2)
        const bool iss = (t + 2 < T_STEPS);
        if (iss) {
            if constexpr (!IN_F32) {
                if (seen < t + 3) {
                    do { seen = flag_load(in_flag); } while (seen < t + 3);
                }
            }
#pragma unroll
            for (int k = 0; k < CPT; ++k) {
                if (sv[k]) {
                    if constexpr (IN_F32) {
                        i32[k] = *reinterpret_cast<const f32x4*>(sgp[k]);
                    } else {
                        i16[k][0] = panel_load((const u64*)sgp[k]);
                        i16[k][1] = panel_load((const u64*)sgp[k] + 1);
                    }
                    sgp[k] += XADVB;
                }
            }
        }

        // (3) A-fragments
        f16x8 a[KT];
#pragma unroll
        for (int kt = 0; kt < KTX; ++kt)
            a[kt] = *reinterpret_cast<const f16x8*>(&xs[pbv][col][kt * 32 + q * 8]);
#pragma unroll
        for (int kt = 0; kt < KTH; ++kt)
            a[KTX + kt] = *reinterpret_cast<const f16x8*>(&hs[pbv][col][kt * 32 + q * 8]);

        // MFMA (single accumulator chain, bias-seeded)
        f32x4 acc[4];
#pragma unroll
        for (int g = 0; g < 4; ++g)
            acc[g] = (f32x4){bias[g], bias[g], bias[g], bias[g]};
#pragma unroll
        for (int kt = 0; kt < KT; ++kt)
#pragma unroll
            for (int g = 0; g < 4; ++g)
                acc[g] = __builtin_amdgcn_mfma_f32_16x16x32_f16(a[kt], bw[g][kt], acc[g], 0, 0, 0);

        // gates (exp2 domain), merged-rcp forms:
        // si*tanh(g)*2L2E = 2L2E*(G-1)/((1+Ei)(G+1)),  h = (C-1)/((1+Eo)(C+1))
#pragma unroll
        for (int r = 0; r < 4; ++r) {
            const float yi = acc[0][r];
            const float yf = acc[1][r];
            const float yg = acc[2][r];   // scaled by 2*log2e
            const float yo = acc[3][r];
            const float Ei = exp2_f(-yi);
            const float G  = exp2_f(yg);                 // e^{2g}
            const float Ef = exp2_f(-yf);
            const float sf = rcp_f(1.0f + Ef);
            const float itg = (2.0f * L2E) * (G - 1.0f) *
                              rcp_f((1.0f + Ei) * (G + 1.0f));   // si * 2L2E*tanh(g)
            cst[r] = fmaf(sf, cst[r], itg);              // c' = 2*log2e*c
            const float C  = exp2_f(cst[r]);             // e^{2c'}
            const float Eo = exp2_f(-yo);
            const float h  = (C - 1.0f) * rcp_f((1.0f + Eo) * (C + 1.0f)); // so*tanh(c')
            hs[pbv ^ 1][4 * q + r][u] = (f16)h;
            if constexpr (!OUT_PANEL) hold[r] = h;
        }

        // (4) commit x(t+1) from regs loaded at step t-1 (no vm stall)
        const bool pf = (t + 1 < T_STEPS);
        if (pf) {
#pragma unroll
            for (int k = 0; k < CPT; ++k) {
                if (sv[k]) {
                    f16* dst = slp[k] + (pbv ^ 1) * LDSD;
                    if constexpr (IN_F32) {
                        f16x4 h4;
                        h4[0] = (f16)c32[k][0]; h4[1] = (f16)c32[k][1];
                        h4[2] = (f16)c32[k][2]; h4[3] = (f16)c32[k][3];
                        *reinterpret_cast<f16x4*>(dst) = h4;
                    } else {
                        *reinterpret_cast<f16x8*>(dst) =
                            *reinterpret_cast<const f16x8*>(c16[k]);
                    }
                }
            }
        }

        // (5) refresh 'seen' only on publish-cadence steps
        if constexpr (!IN_F32) {
            if (dopub && seen < t + 9) seen = flag_load(in_flag);
        }

        if (dodrain) barrier_drain_k<NLOAD>(); else barrier_lgkm();
    };

    for (int tb = 0; tb < T_STEPS; tb += 4) {
        // t even: commit x(t+1) [odd set], issue x(t+2) [even set]; t odd: swap
        step(tb + 0, 0, false, true,  xr32O, xr32E, xr16O, xr16E);
        step(tb + 1, 1, false, false, xr32E, xr32O, xr16E, xr16O);
        step(tb + 2, 0, false, false, xr32O, xr32E, xr16O, xr16E);
        step(tb + 3, 1, true,  false, xr32E, xr32O, xr16E, xr16O);
    }

    // ---- epilogue: final output (h(T-1) in hs[0]), full drain, final flag ----
    if constexpr (OUT_PANEL) {
        u64 v = *reinterpret_cast<const u64*>(olds);
        if constexpr (OUT_TANH) v = tanh4_f16(v);
        panel_store(opg, v);
    } else {
#pragma unroll
        for (int r = 0; r < 4; ++r) outp_f32[r * H] = hold[r];
    }
    barrier_drain();
    if constexpr (OUT_PANEL) {
        if (ltid == 0) flag_store(out_flag, T_STEPS + 4);
    }
}

// Grid (24 blocks x 1024 threads), groups packed for 16 waves / active CU:
//   b 0..7  : L1, 2 groups x 512 thr, LDS 2 x 13312
//   b 8..11 : L2, 4 groups x 128 thr (512 thr; tid >= 512 exits), LDS 4 x 11264
//   b 12..19: L3, 2 groups x 512 thr, LDS 2 x 11264
//   b 20..23: L4, 4 groups x 256 thr, LDS 4 x 13312
// launch_bounds: plain (1024) — compiler caps VGPR at 128 (16-wave residency);
// this kernel needs ~120. DO NOT add a min-occupancy arg (R8: forced 64, spilled).
__global__ __launch_bounds__(1024)
void lstm_fused(const float* __restrict__ X,
                const float* __restrict__ w1_ih, const float* __restrict__ w1_hh,
                const float* __restrict__ b1_ih, const float* __restrict__ b1_hh,
                const float* __restrict__ w2_ih, const float* __restrict__ w2_hh,
                const float* __restrict__ b2_ih, const float* __restrict__ b2_hh,
                const float* __restrict__ w3_ih, const float* __restrict__ w3_hh,
                const float* __restrict__ b3_ih, const float* __restrict__ b3_hh,
                const float* __restrict__ w4_ih, const float* __restrict__ w4_hh,
                const float* __restrict__ b4_ih, const float* __restrict__ b4_hh,
                f16* __restrict__ h1, f16* __restrict__ h2, f16* __restrict__ h3,
                int* __restrict__ flags, float* __restrict__ out)
{
    __shared__ __attribute__((aligned(16))) char smem[53248];
    const int b = blockIdx.x, tid = threadIdx.x;

    if (b < 8) {
        // L1: 64 -> 128, fp32 in, panel out; 2 groups/block
        const int sub = tid >> 9;
        const int g = b * 2 + sub;
        lstm_layer_dev<64, 128, true, true, false>(
            smem + sub * 13312, X, nullptr, flags + 0 * 16 + g,
            w1_ih, w1_hh, b1_ih, b1_hh, h1, g, tid & 511);
    } else if (b < 12) {
        // L2: 128 -> 32, 4 groups x 128 thr; bottleneck tanh on the PANEL
        // path only (recurrence h stays raw). Threads >= 512 exit (HW
        // releases exited waves from the block barrier).
        if (tid >= 512) return;
        const int gl = tid >> 7;
        const int g  = (b - 8) * 4 + gl;
        lstm_layer_dev<128, 32, false, true, true>(
            smem + gl * 11264, h1, flags + 0 * 16 + g, flags + 1 * 16 + g,
            w2_ih, w2_hh, b2_ih, b2_hh, h2, g, tid & 127);
    } else if (b < 20) {
        // L3: 32 -> 128; input panel h2 is already tanh'd; 2 groups/block
        const int sub = tid >> 9;
        const int g = (b - 12) * 2 + sub;
        lstm_layer_dev<32, 128, false, true, false>(
            smem + sub * 11264, h2, flags + 1 * 16 + g, flags + 2 * 16 + g,
            w3_ih, w3_hh, b3_ih, b3_hh, h3, g, tid & 511);
    } else {
        // L4: 128 -> 64, 4 groups x 256 thr, fp32 final out
        const int gl = tid >> 8;
        const int g  = (b - 20) * 4 + gl;
        lstm_layer_dev<128, 64, false, false, false>(
            smem + gl * 13312, h3, flags + 2 * 16 + g, nullptr,
            w4_ih, w4_hh, b4_ih, b4_hh, out, g, tid & 255);
    }
}

extern "C" void kernel_launch(void* const* d_in, const int* in_sizes, int n_in,
                              void* d_out, int out_size, void* d_ws, size_t ws_size,
                              hipStream_t stream) {
    const float* X     = (const float*)d_in[0];
    const float* w1_ih = (const float*)d_in[1];
    const float* w1_hh = (const float*)d_in[2];
    const float* b1_ih = (const float*)d_in[3];
    const float* b1_hh = (const float*)d_in[4];
    const float* w2_ih = (const float*)d_in[5];
    const float* w2_hh = (const float*)d_in[6];
    const float* b2_ih = (const float*)d_in[7];
    const float* b2_hh = (const float*)d_in[8];
    const float* w3_ih = (const float*)d_in[9];
    const float* w3_hh = (const float*)d_in[10];
    const float* b3_ih = (const float*)d_in[11];
    const float* b3_hh = (const float*)d_in[12];
    const float* w4_ih = (const float*)d_in[13];
    const float* w4_hh = (const float*)d_in[14];
    const float* b4_ih = (const float*)d_in[15];
    const float* b4_hh = (const float*)d_in[16];

    float* out = (float*)d_out;

    // ws: flags[48] ints (poison 0xAAAAAAAA < 0 => "not ready"), then f16
    // panels h1 [T,B,128], h2 [T,B,32], h3 [T,B,128]
    int* flags = (int*)d_ws;
    f16* h1 = (f16*)((char*)d_ws + 256);
    f16* h2 = h1 + (size_t)T_STEPS * BATCH * 128;
    f16* h3 = h2 + (size_t)T_STEPS * BATCH * 32;

    lstm_fused<<<24, 1024, 0, stream>>>(X,
        w1_ih, w1_hh, b1_ih, b1_hh, w2_ih, w2_hh, b2_ih, b2_hh,
        w3_ih, w3_hh, b3_ih, b3_hh, w4_ih, w4_hh, b4_ih, b4_hh,
        h1, h2, h3, flags, out);
}

// Round 10
// 711.616 us; speedup vs baseline: 4.2379x; 4.2379x over previous
//
#include <hip/hip_runtime.h>

#define T_STEPS 512
#define BATCH   256

typedef _Float16 f16;
typedef unsigned long long u64;
typedef __attribute__((ext_vector_type(8))) _Float16 f16x8;
typedef __attribute__((ext_vector_type(4))) _Float16 f16x4;
typedef __attribute__((ext_vector_type(4))) float    f32x4;

#define L2E 1.44269504088896340736f

__device__ __forceinline__ float rcp_f(float x)  { return __builtin_amdgcn_rcpf(x); }
__device__ __forceinline__ float exp2_f(float x) { return __builtin_amdgcn_exp2f(x); }

// tanh in exp2 domain: tanh(x) = 1 - 2/(exp2(2*log2e*x)+1)
__device__ __forceinline__ float tanh_n(float x) {
    return fmaf(-2.0f, rcp_f(1.0f + exp2_f(2.0f * L2E * x)), 1.0f);
}
// tanh on 4 packed f16 (bottleneck tanh, applied on L2's panel store)
__device__ __forceinline__ u64 tanh4_f16(u64 v) {
    f16x4 h = __builtin_bit_cast(f16x4, v);
    f16x4 r;
#pragma unroll
    for (int i = 0; i < 4; ++i) r[i] = (f16)tanh_n((float)h[i]);
    return __builtin_bit_cast(u64, r);
}

// Per-step barrier: LDS visibility only (global ops NOT drained).
__device__ __forceinline__ void barrier_lgkm() {
    asm volatile("s_waitcnt lgkmcnt(0)\n\ts_barrier" ::: "memory");
}
// Full drain barrier (pre/epilogue only).
__device__ __forceinline__ void barrier_drain() {
    asm volatile("s_waitcnt vmcnt(0) lgkmcnt(0)\n\ts_barrier" ::: "memory");
}
// Counted drain barrier: wait until <= K vmem ops outstanding. The K newest
// ops are this step's prefetch loads (issued AFTER all stores -> in-order
// vmcnt retirement guarantees every store is retired), so panel stores are
// globally visible without waiting on the fresh sc1 loads.
template <int K>
__device__ __forceinline__ void barrier_drain_k() {
    if constexpr (K == 1)
        asm volatile("s_waitcnt vmcnt(1) lgkmcnt(0)\n\ts_barrier" ::: "memory");
    else if constexpr (K == 2)
        asm volatile("s_waitcnt vmcnt(2) lgkmcnt(0)\n\ts_barrier" ::: "memory");
    else if constexpr (K == 4)
        asm volatile("s_waitcnt vmcnt(4) lgkmcnt(0)\n\ts_barrier" ::: "memory");
    else
        asm volatile("s_waitcnt vmcnt(0) lgkmcnt(0)\n\ts_barrier" ::: "memory");
}

// Agent-scope relaxed atomics -> sc1 ops, coherent at L3 across XCDs.
__device__ __forceinline__ int  flag_load(const int* p) {
    return __hip_atomic_load(p, __ATOMIC_RELAXED, __HIP_MEMORY_SCOPE_AGENT);
}
__device__ __forceinline__ void flag_store(int* p, int v) {
    __hip_atomic_store(p, v, __ATOMIC_RELAXED, __HIP_MEMORY_SCOPE_AGENT);
}
__device__ __forceinline__ u64  panel_load(const u64* p) {
    return __hip_atomic_load(p, __ATOMIC_RELAXED, __HIP_MEMORY_SCOPE_AGENT);
}
__device__ __forceinline__ void panel_store(u64* p, u64 v) {
    __hip_atomic_store(p, v, __ATOMIC_RELAXED, __HIP_MEMORY_SCOPE_AGENT);
}

// One LSTM layer over one 16-batch group (NT = 4H threads). MFMA structure
// verified rounds 2-6 (prior session). Weights/biases scaled by log2e (gates
// i,f,o) and 2*log2e (gate g) at load time; cell state kept in the 2*log2e
// domain; merged-rcp gate forms (8 trans/row, verified identical absmax).
//
// R10 vs R7 (protocol-compatible changes, all targeted at the consumer-side
// flag handshake):
//  (a) 3-step-deep register prefetch: 4 named reg sets A..D; step t commits
//      x(t+1) (issued at t-2, ~2 steps of slack over sc1 latency) and issues
//      x(t+3). Issue requires flag >= t+4.
//  (b) publish cadence 2 (was 4): counted drain at end of every ODD step,
//      flag_store(t-1) at every even t >= 4 — halves watermark staleness.
//  (c) startup lead: consumers' FIRST flag wait is >= 8, so the producer
//      leads by ~10 steps; the cached 'seen' then always covers t+4 between
//      refreshes -> zero blocking polls in steady state.
//  (d) s_setprio(1) around the MFMA+gates dependency chain.
template <int IN_DIM, int H, bool IN_F32, bool OUT_PANEL, bool OUT_TANH>
__device__ __forceinline__ void lstm_layer_dev(
    char* sm,
    const void* __restrict__ xv,       // IN_F32 ? f32 [T,B,IN] : f16 [T,B,IN]
    const int* in_flag,                // upstream flag (unused if IN_F32)
    int* out_flag,                     // our flag (unused if !OUT_PANEL)
    const float* __restrict__ w_ih, const float* __restrict__ w_hh,
    const float* __restrict__ b_ih, const float* __restrict__ b_hh,
    void* __restrict__ outv,           // OUT_PANEL ? f16 [T,B,H] : f32 [T,B,H]
    int group, int ltid)
{
    constexpr int KTX = IN_DIM / 32, KTH = H / 32, KT = KTX + KTH;
    constexpr int XP = IN_DIM + 8, HP = H + 8, NT = 4 * H;

    f16 (*xs)[16][XP] = (f16(*)[16][XP])sm;                       // [2][16][XP]
    f16 (*hs)[16][HP] = (f16(*)[16][HP])(sm + 2 * 16 * XP * 2);   // [2][16][HP]

    const int wave = ltid >> 6, lane = ltid & 63;
    const int col = lane & 15, q = lane >> 4;
    const int bblk = group * 16;
    const int u = wave * 16 + col;

    // ---- one-time: B-fragments (weights, log2e-scaled) -> registers ----
    f16x8 bw[4][KT];
#pragma unroll
    for (int g = 0; g < 4; ++g) {
        const float sc = (g == 2) ? 2.0f * L2E : L2E;
        const int row = g * H + u;
#pragma unroll
        for (int kt = 0; kt < KTX; ++kt) {
            const float* p = w_ih + (size_t)row * IN_DIM + kt * 32 + q * 8;
            f16x8 v;
#pragma unroll
            for (int j = 0; j < 8; ++j) v[j] = (f16)(p[j] * sc);
            bw[g][kt] = v;
        }
#pragma unroll
        for (int kt = 0; kt < KTH; ++kt) {
            const float* p = w_hh + (size_t)row * H + kt * 32 + q * 8;
            f16x8 v;
#pragma unroll
            for (int j = 0; j < 8; ++j) v[j] = (f16)(p[j] * sc);
            bw[g][KTX + kt] = v;
        }
    }
    float bias[4];
#pragma unroll
    for (int g = 0; g < 4; ++g)
        bias[g] = (b_ih[g * H + u] + b_hh[g * H + u]) * ((g == 2) ? 2.0f * L2E : L2E);
    float cst[4] = {0.f, 0.f, 0.f, 0.f};   // cell state, 2*log2e domain

    // ---- input staging: 16B chunks (4 f32 or 8 f16) ----
    constexpr int ELD = IN_F32 ? 4 : 8;
    constexpr int EPR = IN_DIM / ELD;
    constexpr int NCH = 16 * EPR;
    constexpr int CPT = (NCH + NT - 1) / NT;
    constexpr int NLOAD = IN_F32 ? CPT : 2 * CPT;   // load instrs per step
    constexpr long XADVB = (long)BATCH * IN_DIM * (IN_F32 ? 4 : 2);
    bool sv[CPT]; const char* sgp[CPT]; f16* slp[CPT];
    constexpr int LDSD = 16 * XP;          // f16 elems between xs buffers
#pragma unroll
    for (int k = 0; k < CPT; ++k) {
        const int cc = ltid + k * NT;
        sv[k] = (cc < NCH);
        const int r_ = (cc < NCH ? cc : 0) / EPR;
        const int o_ = (cc < NCH ? cc : 0) % EPR;
        sgp[k] = (const char*)xv + ((size_t)(bblk + r_) * IN_DIM + o_ * ELD) * (IN_F32 ? 4 : 2);
        slp[k] = &xs[0][r_][o_ * ELD];
    }

    // ---- output setup ----
    constexpr int OEPR = H / 4;            // u64 chunks per row; NT == 16*OEPR
    u64* opg = nullptr;
    f16* olds = nullptr;
    float* outp_f32 = nullptr;
    if constexpr (OUT_PANEL) {
        const int orow = ltid / OEPR, ooff = ltid % OEPR;
        opg  = (u64*)((f16*)outv + (size_t)(bblk + orow) * H) + ooff;
        olds = &hs[0][orow][ooff * 4];
    } else {
        outp_f32 = (float*)outv + ((size_t)bblk + 4 * q) * H + u;
    }
    constexpr int HLDSD = 16 * HP;

    // ---- pre-loop: zero h(0); wait upstream (lead >= 8); stage x(0);
    //      issue x(1) -> set B, x(2) -> set C ----
    for (int i = ltid; i < 16 * HP; i += NT) hs[0][i / HP][i % HP] = (f16)0.f;
    int seen = 0;
    if constexpr (!IN_F32) {
        do { seen = flag_load(in_flag); } while (seen < 8);   // startup lead
    }
#pragma unroll
    for (int k = 0; k < CPT; ++k) {
        if (sv[k]) {
            if constexpr (IN_F32) {
                const f32x4 v = *reinterpret_cast<const f32x4*>(sgp[k]);
                f16x4 h4;
                h4[0] = (f16)v[0]; h4[1] = (f16)v[1]; h4[2] = (f16)v[2]; h4[3] = (f16)v[3];
                *reinterpret_cast<f16x4*>(slp[k]) = h4;
            } else {
                u64 a = panel_load((const u64*)sgp[k]);
                u64 b = panel_load((const u64*)sgp[k] + 1);
                u64 pk[2] = {a, b};
                *reinterpret_cast<f16x8*>(slp[k]) = *reinterpret_cast<const f16x8*>(pk);
            }
            sgp[k] += XADVB;
        }
    }
    // prefetch register sets: x(k) k%4==1 -> B, 2 -> C, 3 -> D, 0 -> A
    f32x4 xr32A[CPT], xr32B[CPT], xr32C[CPT], xr32D[CPT];
    u64 xr16A[CPT][2], xr16B[CPT][2], xr16C[CPT][2], xr16D[CPT][2];
#pragma unroll
    for (int k = 0; k < CPT; ++k) {
        xr32A[k] = f32x4{}; xr32D[k] = f32x4{};
        xr16A[k][0] = xr16A[k][1] = 0; xr16D[k][0] = xr16D[k][1] = 0;
        if (sv[k]) {
            if constexpr (IN_F32) {
                xr32B[k] = *reinterpret_cast<const f32x4*>(sgp[k]);            // x(1)
                xr32C[k] = *reinterpret_cast<const f32x4*>(sgp[k] + XADVB);    // x(2)
            } else {
                xr16B[k][0] = panel_load((const u64*)sgp[k]);
                xr16B[k][1] = panel_load((const u64*)sgp[k] + 1);
                xr16C[k][0] = panel_load((const u64*)(sgp[k] + XADVB));
                xr16C[k][1] = panel_load((const u64*)(sgp[k] + XADVB) + 1);
            }
            sgp[k] += 2 * XADVB;
        } else {
            xr32B[k] = f32x4{}; xr32C[k] = f32x4{};
            xr16B[k][0] = xr16B[k][1] = 0; xr16C[k][0] = xr16C[k][1] = 0;
        }
    }
    barrier_lgkm();   // prefetch loads stay in flight across the barrier

    float hold[4] = {0.f, 0.f, 0.f, 0.f};

    // ---- one step; pbv/dodrain/dopub are literal at each call site.
    //      c* = set holding x(t+1) (issued at t-2); i* = set receiving x(t+3).
    auto step = [&](int t, int pbv, bool dodrain, bool dopub,
                    f32x4 (&c32)[CPT], f32x4 (&i32)[CPT],
                    u64 (&c16)[CPT][2], u64 (&i16)[CPT][2]) {
        if constexpr (OUT_PANEL) {
            if (dopub && t >= 4 && ltid == 0) flag_store(out_flag, t - 1);
        }

        // (1) write step t-1's output FIRST (h(t-1) sits in hs[pbv]) so the
        //     counted drain covers all stores without touching fresh loads
        if (t >= 1) {
            if constexpr (OUT_PANEL) {
                u64 v = *reinterpret_cast<const u64*>(olds + pbv * HLDSD);
                if constexpr (OUT_TANH) v = tanh4_f16(v);
                panel_store(opg, v);
                opg += (size_t)BATCH * H / 4;
            } else {
#pragma unroll
                for (int r = 0; r < 4; ++r) outp_f32[r * H] = hold[r];
                outp_f32 += (size_t)BATCH * H;
            }
        }

        // (2) issue prefetch of x(t+3) (needs flag >= t+4; never blocks in
        //     steady state thanks to the startup lead + cadence-2 refresh)
        const bool iss = (t + 3 < T_STEPS);
        if (iss) {
            if constexpr (!IN_F32) {
                if (seen < t + 4) {
                    do { seen = flag_load(in_flag); } while (seen < t + 4);
                }
            }
#pragma unroll
            for (int k = 0; k < CPT; ++k) {
                if (sv[k]) {
                    if constexpr (IN_F32) {
                        i32[k] = *reinterpret_cast<const f32x4*>(sgp[k]);
                    } else {
                        i16[k][0] = panel_load((const u64*)sgp[k]);
                        i16[k][1] = panel_load((const u64*)sgp[k] + 1);
                    }
                    sgp[k] += XADVB;
                }
            }
        }

        // (3) A-fragments + MFMA + gates (the serial chain) at raised prio
        f16x8 a[KT];
#pragma unroll
        for (int kt = 0; kt < KTX; ++kt)
            a[kt] = *reinterpret_cast<const f16x8*>(&xs[pbv][col][kt * 32 + q * 8]);
#pragma unroll
        for (int kt = 0; kt < KTH; ++kt)
            a[KTX + kt] = *reinterpret_cast<const f16x8*>(&hs[pbv][col][kt * 32 + q * 8]);

        __builtin_amdgcn_s_setprio(1);
        f32x4 acc[4];
#pragma unroll
        for (int g = 0; g < 4; ++g)
            acc[g] = (f32x4){bias[g], bias[g], bias[g], bias[g]};
#pragma unroll
        for (int kt = 0; kt < KT; ++kt)
#pragma unroll
            for (int g = 0; g < 4; ++g)
                acc[g] = __builtin_amdgcn_mfma_f32_16x16x32_f16(a[kt], bw[g][kt], acc[g], 0, 0, 0);

        // gates (exp2 domain), merged-rcp forms:
        // si*tanh(g)*2L2E = 2L2E*(G-1)/((1+Ei)(G+1)),  h = (C-1)/((1+Eo)(C+1))
#pragma unroll
        for (int r = 0; r < 4; ++r) {
            const float yi = acc[0][r];
            const float yf = acc[1][r];
            const float yg = acc[2][r];   // scaled by 2*log2e
            const float yo = acc[3][r];
            const float Ei = exp2_f(-yi);
            const float G  = exp2_f(yg);                 // e^{2g}
            const float Ef = exp2_f(-yf);
            const float sf = rcp_f(1.0f + Ef);
            const float itg = (2.0f * L2E) * (G - 1.0f) *
                              rcp_f((1.0f + Ei) * (G + 1.0f));   // si * 2L2E*tanh(g)
            cst[r] = fmaf(sf, cst[r], itg);              // c' = 2*log2e*c
            const float C  = exp2_f(cst[r]);             // e^{2c'}
            const float Eo = exp2_f(-yo);
            const float h  = (C - 1.0f) * rcp_f((1.0f + Eo) * (C + 1.0f)); // so*tanh(c')
            hs[pbv ^ 1][4 * q + r][u] = (f16)h;
            if constexpr (!OUT_PANEL) hold[r] = h;
        }
        __builtin_amdgcn_s_setprio(0);

        // (4) commit x(t+1) from regs issued at step t-2 (no vm stall)
        const bool pf = (t + 1 < T_STEPS);
        if (pf) {
#pragma unroll
            for (int k = 0; k < CPT; ++k) {
                if (sv[k]) {
                    f16* dst = slp[k] + (pbv ^ 1) * LDSD;
                    if constexpr (IN_F32) {
                        f16x4 h4;
                        h4[0] = (f16)c32[k][0]; h4[1] = (f16)c32[k][1];
                        h4[2] = (f16)c32[k][2]; h4[3] = (f16)c32[k][3];
                        *reinterpret_cast<f16x4*>(dst) = h4;
                    } else {
                        *reinterpret_cast<f16x8*>(dst) =
                            *reinterpret_cast<const f16x8*>(c16[k]);
                    }
                }
            }
        }

        // (5) refresh 'seen' on publish-cadence steps (load consumed next
        //     step -> latency covered; keeps the blocking poll dormant)
        if constexpr (!IN_F32) {
            if (dopub && seen < t + 9) seen = flag_load(in_flag);
        }

        if (dodrain) barrier_drain_k<NLOAD>(); else barrier_lgkm();
    };

    // set rotation: x(k) k%4==1 -> B, 2 -> C, 3 -> D, 0 -> A.
    // step t commits set[(t+1)%4], issues x(t+3) into set[(t+3)%4].
    // drain at end of every ODD step; publish at every even step (t>=4).
    for (int tb = 0; tb < T_STEPS; tb += 4) {
        step(tb + 0, 0, false, true,  xr32B, xr32D, xr16B, xr16D);
        step(tb + 1, 1, true,  false, xr32C, xr32A, xr16C, xr16A);
        step(tb + 2, 0, false, true,  xr32D, xr32B, xr16D, xr16B);
        step(tb + 3, 1, true,  false, xr32A, xr32C, xr16A, xr16C);
    }

    // ---- epilogue: final output (h(T-1) in hs[0]), full drain, final flag ----
    if constexpr (OUT_PANEL) {
        u64 v = *reinterpret_cast<const u64*>(olds);
        if constexpr (OUT_TANH) v = tanh4_f16(v);
        panel_store(opg, v);
    } else {
#pragma unroll
        for (int r = 0; r < 4; ++r) outp_f32[r * H] = hold[r];
    }
    barrier_drain();
    if constexpr (OUT_PANEL) {
        if (ltid == 0) flag_store(out_flag, T_STEPS + 8);
    }
}

__global__ __launch_bounds__(512, 1)
void lstm_fused(const float* __restrict__ X,
                const float* __restrict__ w1_ih, const float* __restrict__ w1_hh,
                const float* __restrict__ b1_ih, const float* __restrict__ b1_hh,
                const float* __restrict__ w2_ih, const float* __restrict__ w2_hh,
                const float* __restrict__ b2_ih, const float* __restrict__ b2_hh,
                const float* __restrict__ w3_ih, const float* __restrict__ w3_hh,
                const float* __restrict__ b3_ih, const float* __restrict__ b3_hh,
                const float* __restrict__ w4_ih, const float* __restrict__ w4_hh,
                const float* __restrict__ b4_ih, const float* __restrict__ b4_hh,
                f16* __restrict__ h1, f16* __restrict__ h2, f16* __restrict__ h3,
                int* __restrict__ flags, float* __restrict__ out)
{
    __shared__ __attribute__((aligned(16))) char smem[45056];
    const int b = blockIdx.x, tid = threadIdx.x;

    if (b < 16) {
        // L1: 64 -> 128, fp32 in, panel out, 1 group/block (512 thr)
        lstm_layer_dev<64, 128, true, true, false>(
            smem, X, nullptr, flags + 0 * 16 + b,
            w1_ih, w1_hh, b1_ih, b1_hh, h1, b, tid);
    } else if (b < 20) {
        // L2: 128 -> 32, 4 groups/block (128 thr each); bottleneck tanh is
        // applied on the PANEL path only (recurrence h stays raw)
        const int gl = tid >> 7;
        const int g  = (b - 16) * 4 + gl;
        lstm_layer_dev<128, 32, false, true, true>(
            smem + gl * 11264, h1, flags + 0 * 16 + g, flags + 1 * 16 + g,
            w2_ih, w2_hh, b2_ih, b2_hh, h2, g, tid & 127);
    } else if (b < 36) {
        // L3: 32 -> 128; input panel h2 is already tanh'd
        const int g = b - 20;
        lstm_layer_dev<32, 128, false, true, false>(
            smem, h2, flags + 1 * 16 + g, flags + 2 * 16 + g,
            w3_ih, w3_hh, b3_ih, b3_hh, h3, g, tid);
    } else {
        // L4: 128 -> 64, 2 groups/block (256 thr each), fp32 final out
        const int gl = tid >> 8;
        const int g  = (b - 36) * 2 + gl;
        lstm_layer_dev<128, 64, false, false, false>(
            smem + gl * 13312, h3, flags + 2 * 16 + g, nullptr,
            w4_ih, w4_hh, b4_ih, b4_hh, out, g, tid & 255);
    }
}

extern "C" void kernel_launch(void* const* d_in, const int* in_sizes, int n_in,
                              void* d_out, int out_size, void* d_ws, size_t ws_size,
                              hipStream_t stream) {
    const float* X     = (const float*)d_in[0];
    const float* w1_ih = (const float*)d_in[1];
    const float* w1_hh = (const float*)d_in[2];
    const float* b1_ih = (const float*)d_in[3];
    const float* b1_hh = (const float*)d_in[4];
    const float* w2_ih = (const float*)d_in[5];
    const float* w2_hh = (const float*)d_in[6];
    const float* b2_ih = (const float*)d_in[7];
    const float* b2_hh = (const float*)d_in[8];
    const float* w3_ih = (const float*)d_in[9];
    const float* w3_hh = (const float*)d_in[10];
    const float* b3_ih = (const float*)d_in[11];
    const float* b3_hh = (const float*)d_in[12];
    const float* w4_ih = (const float*)d_in[13];
    const float* w4_hh = (const float*)d_in[14];
    const float* b4_ih = (const float*)d_in[15];
    const float* b4_hh = (const float*)d_in[16];

    float* out = (float*)d_out;

    // ws: flags[48] ints (poison 0xAAAAAAAA < 0 => "not ready"), then f16
    // panels h1 [T,B,128], h2 [T,B,32], h3 [T,B,128]
    int* flags = (int*)d_ws;
    f16* h1 = (f16*)((char*)d_ws + 256);
    f16* h2 = h1 + (size_t)T_STEPS * BATCH * 128;
    f16* h3 = h2 + (size_t)T_STEPS * BATCH * 32;

    lstm_fused<<<44, 512, 0, stream>>>(X,
        w1_ih, w1_hh, b1_ih, b1_hh, w2_ih, w2_hh, b2_ih, b2_hh,
        w3_ih, w3_hh, b3_ih, b3_hh, w4_ih, w4_hh, b4_ih, b4_hh,
        h1, h2, h3, flags, out);
}

// Round 11
// 637.493 us; speedup vs baseline: 4.7307x; 1.1163x over previous
//
#include <hip/hip_runtime.h>

#define T_STEPS 512
#define BATCH   256

typedef _Float16 f16;
typedef unsigned long long u64;
typedef __attribute__((ext_vector_type(8))) _Float16 f16x8;
typedef __attribute__((ext_vector_type(4))) _Float16 f16x4;
typedef __attribute__((ext_vector_type(4))) float    f32x4;

#define L2E 1.44269504088896340736f

__device__ __forceinline__ float rcp_f(float x)  { return __builtin_amdgcn_rcpf(x); }
__device__ __forceinline__ float exp2_f(float x) { return __builtin_amdgcn_exp2f(x); }

// tanh in exp2 domain: tanh(x) = 1 - 2/(exp2(2*log2e*x)+1)
__device__ __forceinline__ float tanh_n(float x) {
    return fmaf(-2.0f, rcp_f(1.0f + exp2_f(2.0f * L2E * x)), 1.0f);
}
// tanh on 4 packed f16 (bottleneck tanh, applied on L2's panel store)
__device__ __forceinline__ u64 tanh4_f16(u64 v) {
    f16x4 h = __builtin_bit_cast(f16x4, v);
    f16x4 r;
#pragma unroll
    for (int i = 0; i < 4; ++i) r[i] = (f16)tanh_n((float)h[i]);
    return __builtin_bit_cast(u64, r);
}

// Per-step barrier: LDS visibility only (global ops NOT drained).
__device__ __forceinline__ void barrier_lgkm() {
    asm volatile("s_waitcnt lgkmcnt(0)\n\ts_barrier" ::: "memory");
}
// Full drain barrier (pre/epilogue only).
__device__ __forceinline__ void barrier_drain() {
    asm volatile("s_waitcnt vmcnt(0) lgkmcnt(0)\n\ts_barrier" ::: "memory");
}
// Counted drain barrier: wait until <= K vmem ops outstanding. With
// K = NLOAD+1, the K newest ops are this step's prefetch loads AND this
// step's output store — the drain only asserts stores from PREVIOUS steps
// (>= 1 full step old, sc1 retire long done) => ~zero stall. The published
// flag is correspondingly t-2, not t-1.
template <int K>
__device__ __forceinline__ void barrier_drain_k() {
    if constexpr (K == 1)
        asm volatile("s_waitcnt vmcnt(1) lgkmcnt(0)\n\ts_barrier" ::: "memory");
    else if constexpr (K == 2)
        asm volatile("s_waitcnt vmcnt(2) lgkmcnt(0)\n\ts_barrier" ::: "memory");
    else if constexpr (K == 3)
        asm volatile("s_waitcnt vmcnt(3) lgkmcnt(0)\n\ts_barrier" ::: "memory");
    else if constexpr (K == 4)
        asm volatile("s_waitcnt vmcnt(4) lgkmcnt(0)\n\ts_barrier" ::: "memory");
    else if constexpr (K == 5)
        asm volatile("s_waitcnt vmcnt(5) lgkmcnt(0)\n\ts_barrier" ::: "memory");
    else
        asm volatile("s_waitcnt vmcnt(0) lgkmcnt(0)\n\ts_barrier" ::: "memory");
}

// Agent-scope relaxed atomics -> sc1 ops, coherent at L3 across XCDs.
__device__ __forceinline__ int  flag_load(const int* p) {
    return __hip_atomic_load(p, __ATOMIC_RELAXED, __HIP_MEMORY_SCOPE_AGENT);
}
__device__ __forceinline__ void flag_store(int* p, int v) {
    __hip_atomic_store(p, v, __ATOMIC_RELAXED, __HIP_MEMORY_SCOPE_AGENT);
}
__device__ __forceinline__ u64  panel_load(const u64* p) {
    return __hip_atomic_load(p, __ATOMIC_RELAXED, __HIP_MEMORY_SCOPE_AGENT);
}
__device__ __forceinline__ void panel_store(u64* p, u64 v) {
    __hip_atomic_store(p, v, __ATOMIC_RELAXED, __HIP_MEMORY_SCOPE_AGENT);
}

// One LSTM layer over one 16-batch group (NT = 4H threads). MFMA structure
// verified rounds 2-6 (prior session). Weights/biases scaled by log2e (gates
// i,f,o) and 2*log2e (gate g) at load time; cell state kept in the 2*log2e
// domain; merged-rcp gate forms (8 trans/row, verified identical absmax).
//
// R11 vs R7 (handshake-only; ONE mechanism this time — R10 bundled and the
// cadence-2 drains dominated as a regression):
//  (a) drain K = NLOAD+1 and publish flag = t-2: the counted drain never
//      waits on the store issued in the same step (sc1 retire off-path).
//  (b) consumer startup gate: first flag wait >= 8 (was >= 1), making the
//      steady-state producer lead ~12 steps — the every-4th-step blocking
//      poll (a ~400-700cy L3 round trip) goes dormant. Cadence stays 4.
//  (c) L4 (no out-flag) never drains in-loop.
// Pipeline: flag f = "panels 0..f-1 globally visible"; producer publishes
// f = s-2 at steps s%4==0 (after K=NLOAD+1 drain at end of s-1).
template <int IN_DIM, int H, bool IN_F32, bool OUT_PANEL, bool OUT_TANH>
__device__ __forceinline__ void lstm_layer_dev(
    char* sm,
    const void* __restrict__ xv,       // IN_F32 ? f32 [T,B,IN] : f16 [T,B,IN]
    const int* in_flag,                // upstream flag (unused if IN_F32)
    int* out_flag,                     // our flag (unused if !OUT_PANEL)
    const float* __restrict__ w_ih, const float* __restrict__ w_hh,
    const float* __restrict__ b_ih, const float* __restrict__ b_hh,
    void* __restrict__ outv,           // OUT_PANEL ? f16 [T,B,H] : f32 [T,B,H]
    int group, int ltid)
{
    constexpr int KTX = IN_DIM / 32, KTH = H / 32, KT = KTX + KTH;
    constexpr int XP = IN_DIM + 8, HP = H + 8, NT = 4 * H;

    f16 (*xs)[16][XP] = (f16(*)[16][XP])sm;                       // [2][16][XP]
    f16 (*hs)[16][HP] = (f16(*)[16][HP])(sm + 2 * 16 * XP * 2);   // [2][16][HP]

    const int wave = ltid >> 6, lane = ltid & 63;
    const int col = lane & 15, q = lane >> 4;
    const int bblk = group * 16;
    const int u = wave * 16 + col;

    // ---- one-time: B-fragments (weights, log2e-scaled) -> registers ----
    f16x8 bw[4][KT];
#pragma unroll
    for (int g = 0; g < 4; ++g) {
        const float sc = (g == 2) ? 2.0f * L2E : L2E;
        const int row = g * H + u;
#pragma unroll
        for (int kt = 0; kt < KTX; ++kt) {
            const float* p = w_ih + (size_t)row * IN_DIM + kt * 32 + q * 8;
            f16x8 v;
#pragma unroll
            for (int j = 0; j < 8; ++j) v[j] = (f16)(p[j] * sc);
            bw[g][kt] = v;
        }
#pragma unroll
        for (int kt = 0; kt < KTH; ++kt) {
            const float* p = w_hh + (size_t)row * H + kt * 32 + q * 8;
            f16x8 v;
#pragma unroll
            for (int j = 0; j < 8; ++j) v[j] = (f16)(p[j] * sc);
            bw[g][KTX + kt] = v;
        }
    }
    float bias[4];
#pragma unroll
    for (int g = 0; g < 4; ++g)
        bias[g] = (b_ih[g * H + u] + b_hh[g * H + u]) * ((g == 2) ? 2.0f * L2E : L2E);
    float cst[4] = {0.f, 0.f, 0.f, 0.f};   // cell state, 2*log2e domain

    // ---- input staging: 16B chunks (4 f32 or 8 f16) ----
    constexpr int ELD = IN_F32 ? 4 : 8;
    constexpr int EPR = IN_DIM / ELD;
    constexpr int NCH = 16 * EPR;
    constexpr int CPT = (NCH + NT - 1) / NT;
    constexpr int NLOAD = IN_F32 ? CPT : 2 * CPT;   // load instrs per step
    constexpr long XADVB = (long)BATCH * IN_DIM * (IN_F32 ? 4 : 2);
    bool sv[CPT]; const char* sgp[CPT]; f16* slp[CPT];
    constexpr int LDSD = 16 * XP;          // f16 elems between xs buffers
#pragma unroll
    for (int k = 0; k < CPT; ++k) {
        const int cc = ltid + k * NT;
        sv[k] = (cc < NCH);
        const int r_ = (cc < NCH ? cc : 0) / EPR;
        const int o_ = (cc < NCH ? cc : 0) % EPR;
        sgp[k] = (const char*)xv + ((size_t)(bblk + r_) * IN_DIM + o_ * ELD) * (IN_F32 ? 4 : 2);
        slp[k] = &xs[0][r_][o_ * ELD];
    }

    // ---- output setup ----
    constexpr int OEPR = H / 4;            // u64 chunks per row; NT == 16*OEPR
    u64* opg = nullptr;
    f16* olds = nullptr;
    float* outp_f32 = nullptr;
    if constexpr (OUT_PANEL) {
        const int orow = ltid / OEPR, ooff = ltid % OEPR;
        opg  = (u64*)((f16*)outv + (size_t)(bblk + orow) * H) + ooff;
        olds = &hs[0][orow][ooff * 4];
    } else {
        outp_f32 = (float*)outv + ((size_t)bblk + 4 * q) * H + u;
    }
    constexpr int HLDSD = 16 * HP;

    // ---- pre-loop: zero h(0); startup gate (lead >= 8); stage x(0);
    //      issue x(1) into the ODD reg set ----
    for (int i = ltid; i < 16 * HP; i += NT) hs[0][i / HP][i % HP] = (f16)0.f;
    int seen = 0;
    if constexpr (!IN_F32) {
        do { seen = flag_load(in_flag); } while (seen < 8);   // startup gate
    }
#pragma unroll
    for (int k = 0; k < CPT; ++k) {
        if (sv[k]) {
            if constexpr (IN_F32) {
                const f32x4 v = *reinterpret_cast<const f32x4*>(sgp[k]);
                f16x4 h4;
                h4[0] = (f16)v[0]; h4[1] = (f16)v[1]; h4[2] = (f16)v[2]; h4[3] = (f16)v[3];
                *reinterpret_cast<f16x4*>(slp[k]) = h4;
            } else {
                u64 a = panel_load((const u64*)sgp[k]);
                u64 b = panel_load((const u64*)sgp[k] + 1);
                u64 pk[2] = {a, b};
                *reinterpret_cast<f16x8*>(slp[k]) = *reinterpret_cast<const f16x8*>(pk);
            }
            sgp[k] += XADVB;
        }
    }
    // issue x(1) into the ODD reg set (consumed at step 0's commit)
    f32x4 xr32O[CPT], xr32E[CPT];
    u64 xr16O[CPT][2], xr16E[CPT][2];
#pragma unroll
    for (int k = 0; k < CPT; ++k) {
        if (sv[k]) {
            if constexpr (IN_F32) {
                xr32O[k] = *reinterpret_cast<const f32x4*>(sgp[k]);
            } else {
                xr16O[k][0] = panel_load((const u64*)sgp[k]);
                xr16O[k][1] = panel_load((const u64*)sgp[k] + 1);
            }
            sgp[k] += XADVB;
        }
    }
    barrier_lgkm();   // x(1) loads stay in flight across the barrier

    float hold[4] = {0.f, 0.f, 0.f, 0.f};

    // ---- one step; pbv/dodrain/dopub are literal at each call site.
    //      c* holds x(t+1) (loaded at t-1); i* receives x(t+2). ----
    auto step = [&](int t, int pbv, bool dodrain, bool dopub,
                    f32x4 (&c32)[CPT], f32x4 (&i32)[CPT],
                    u64 (&c16)[CPT][2], u64 (&i16)[CPT][2]) {
        if constexpr (OUT_PANEL) {
            // flag = t-2: the K=NLOAD+1 drain at end of t-1 asserted stores
            // through panel t-3 => panels 0..t-3 visible; f means < f.
            if (dopub && t >= 4 && ltid == 0) flag_store(out_flag, t - 2);
        }

        // (1) write step t-1's output FIRST (h(t-1) sits in hs[pbv]) so the
        //     counted drain covers all prior stores without touching fresh ops
        if (t >= 1) {
            if constexpr (OUT_PANEL) {
                u64 v = *reinterpret_cast<const u64*>(olds + pbv * HLDSD);
                if constexpr (OUT_TANH) v = tanh4_f16(v);
                panel_store(opg, v);
                opg += (size_t)BATCH * H / 4;
            } else {
#pragma unroll
                for (int r = 0; r < 4; ++r) outp_f32[r * H] = hold[r];
                outp_f32 += (size_t)BATCH * H;
            }
        }

        // (2) issue prefetch of x(t+2); with the startup gate the cached
        //     'seen' normally already covers t+3 -> no blocking poll
        const bool iss = (t + 2 < T_STEPS);
        if (iss) {
            if constexpr (!IN_F32) {
                if (seen < t + 3) {
                    do { seen = flag_load(in_flag); } while (seen < t + 3);
                }
            }
#pragma unroll
            for (int k = 0; k < CPT; ++k) {
                if (sv[k]) {
                    if constexpr (IN_F32) {
                        i32[k] = *reinterpret_cast<const f32x4*>(sgp[k]);
                    } else {
                        i16[k][0] = panel_load((const u64*)sgp[k]);
                        i16[k][1] = panel_load((const u64*)sgp[k] + 1);
                    }
                    sgp[k] += XADVB;
                }
            }
        }

        // (3) A-fragments
        f16x8 a[KT];
#pragma unroll
        for (int kt = 0; kt < KTX; ++kt)
            a[kt] = *reinterpret_cast<const f16x8*>(&xs[pbv][col][kt * 32 + q * 8]);
#pragma unroll
        for (int kt = 0; kt < KTH; ++kt)
            a[KTX + kt] = *reinterpret_cast<const f16x8*>(&hs[pbv][col][kt * 32 + q * 8]);

        // MFMA (single accumulator chain, bias-seeded)
        f32x4 acc[4];
#pragma unroll
        for (int g = 0; g < 4; ++g)
            acc[g] = (f32x4){bias[g], bias[g], bias[g], bias[g]};
#pragma unroll
        for (int kt = 0; kt < KT; ++kt)
#pragma unroll
            for (int g = 0; g < 4; ++g)
                acc[g] = __builtin_amdgcn_mfma_f32_16x16x32_f16(a[kt], bw[g][kt], acc[g], 0, 0, 0);

        // gates (exp2 domain), merged-rcp forms:
        // si*tanh(g)*2L2E = 2L2E*(G-1)/((1+Ei)(G+1)),  h = (C-1)/((1+Eo)(C+1))
#pragma unroll
        for (int r = 0; r < 4; ++r) {
            const float yi = acc[0][r];
            const float yf = acc[1][r];
            const float yg = acc[2][r];   // scaled by 2*log2e
            const float yo = acc[3][r];
            const float Ei = exp2_f(-yi);
            const float G  = exp2_f(yg);                 // e^{2g}
            const float Ef = exp2_f(-yf);
            const float sf = rcp_f(1.0f + Ef);
            const float itg = (2.0f * L2E) * (G - 1.0f) *
                              rcp_f((1.0f + Ei) * (G + 1.0f));   // si * 2L2E*tanh(g)
            cst[r] = fmaf(sf, cst[r], itg);              // c' = 2*log2e*c
            const float C  = exp2_f(cst[r]);             // e^{2c'}
            const float Eo = exp2_f(-yo);
            const float h  = (C - 1.0f) * rcp_f((1.0f + Eo) * (C + 1.0f)); // so*tanh(c')
            hs[pbv ^ 1][4 * q + r][u] = (f16)h;
            if constexpr (!OUT_PANEL) hold[r] = h;
        }

        // (4) commit x(t+1) from regs loaded at step t-1 (no vm stall)
        const bool pf = (t + 1 < T_STEPS);
        if (pf) {
#pragma unroll
            for (int k = 0; k < CPT; ++k) {
                if (sv[k]) {
                    f16* dst = slp[k] + (pbv ^ 1) * LDSD;
                    if constexpr (IN_F32) {
                        f16x4 h4;
                        h4[0] = (f16)c32[k][0]; h4[1] = (f16)c32[k][1];
                        h4[2] = (f16)c32[k][2]; h4[3] = (f16)c32[k][3];
                        *reinterpret_cast<f16x4*>(dst) = h4;
                    } else {
                        *reinterpret_cast<f16x8*>(dst) =
                            *reinterpret_cast<const f16x8*>(c16[k]);
                    }
                }
            }
        }

        // (5) refresh 'seen' on publish-cadence steps (result consumed next
        //     step at the earliest -> latency covered)
        if constexpr (!IN_F32) {
            if (dopub) seen = flag_load(in_flag);
        }

        if (dodrain) {
            if constexpr (OUT_PANEL) barrier_drain_k<NLOAD + 1>();
            else barrier_lgkm();          // L4: no flag -> no drain needed
        } else {
            barrier_lgkm();
        }
    };

    for (int tb = 0; tb < T_STEPS; tb += 4) {
        // t even: commit x(t+1) [odd set], issue x(t+2) [even set]; t odd: swap
        step(tb + 0, 0, false, true,  xr32O, xr32E, xr16O, xr16E);
        step(tb + 1, 1, false, false, xr32E, xr32O, xr16E, xr16O);
        step(tb + 2, 0, false, false, xr32O, xr32E, xr16O, xr16E);
        step(tb + 3, 1, true,  false, xr32E, xr32O, xr16E, xr16O);
    }

    // ---- epilogue: final output (h(T-1) in hs[0]), full drain, final flag ----
    if constexpr (OUT_PANEL) {
        u64 v = *reinterpret_cast<const u64*>(olds);
        if constexpr (OUT_TANH) v = tanh4_f16(v);
        panel_store(opg, v);
    } else {
#pragma unroll
        for (int r = 0; r < 4; ++r) outp_f32[r * H] = hold[r];
    }
    barrier_drain();
    if constexpr (OUT_PANEL) {
        if (ltid == 0) flag_store(out_flag, T_STEPS + 8);
    }
}

__global__ __launch_bounds__(512, 1)
void lstm_fused(const float* __restrict__ X,
                const float* __restrict__ w1_ih, const float* __restrict__ w1_hh,
                const float* __restrict__ b1_ih, const float* __restrict__ b1_hh,
                const float* __restrict__ w2_ih, const float* __restrict__ w2_hh,
                const float* __restrict__ b2_ih, const float* __restrict__ b2_hh,
                const float* __restrict__ w3_ih, const float* __restrict__ w3_hh,
                const float* __restrict__ b3_ih, const float* __restrict__ b3_hh,
                const float* __restrict__ w4_ih, const float* __restrict__ w4_hh,
                const float* __restrict__ b4_ih, const float* __restrict__ b4_hh,
                f16* __restrict__ h1, f16* __restrict__ h2, f16* __restrict__ h3,
                int* __restrict__ flags, float* __restrict__ out)
{
    __shared__ __attribute__((aligned(16))) char smem[45056];
    const int b = blockIdx.x, tid = threadIdx.x;

    if (b < 16) {
        // L1: 64 -> 128, fp32 in, panel out, 1 group/block (512 thr)
        lstm_layer_dev<64, 128, true, true, false>(
            smem, X, nullptr, flags + 0 * 16 + b,
            w1_ih, w1_hh, b1_ih, b1_hh, h1, b, tid);
    } else if (b < 20) {
        // L2: 128 -> 32, 4 groups/block (128 thr each); bottleneck tanh is
        // applied on the PANEL path only (recurrence h stays raw)
        const int gl = tid >> 7;
        const int g  = (b - 16) * 4 + gl;
        lstm_layer_dev<128, 32, false, true, true>(
            smem + gl * 11264, h1, flags + 0 * 16 + g, flags + 1 * 16 + g,
            w2_ih, w2_hh, b2_ih, b2_hh, h2, g, tid & 127);
    } else if (b < 36) {
        // L3: 32 -> 128; input panel h2 is already tanh'd
        const int g = b - 20;
        lstm_layer_dev<32, 128, false, true, false>(
            smem, h2, flags + 1 * 16 + g, flags + 2 * 16 + g,
            w3_ih, w3_hh, b3_ih, b3_hh, h3, g, tid);
    } else {
        // L4: 128 -> 64, 2 groups/block (256 thr each), fp32 final out
        const int gl = tid >> 8;
        const int g  = (b - 36) * 2 + gl;
        lstm_layer_dev<128, 64, false, false, false>(
            smem + gl * 13312, h3, flags + 2 * 16 + g, nullptr,
            w4_ih, w4_hh, b4_ih, b4_hh, out, g, tid & 255);
    }
}

extern "C" void kernel_launch(void* const* d_in, const int* in_sizes, int n_in,
                              void* d_out, int out_size, void* d_ws, size_t ws_size,
                              hipStream_t stream) {
    const float* X     = (const float*)d_in[0];
    const float* w1_ih = (const float*)d_in[1];
    const float* w1_hh = (const float*)d_in[2];
    const float* b1_ih = (const float*)d_in[3];
    const float* b1_hh = (const float*)d_in[4];
    const float* w2_ih = (const float*)d_in[5];
    const float* w2_hh = (const float*)d_in[6];
    const float* b2_ih = (const float*)d_in[7];
    const float* b2_hh = (const float*)d_in[8];
    const float* w3_ih = (const float*)d_in[9];
    const float* w3_hh = (const float*)d_in[10];
    const float* b3_ih = (const float*)d_in[11];
    const float* b3_hh = (const float*)d_in[12];
    const float* w4_ih = (const float*)d_in[13];
    const float* w4_hh = (const float*)d_in[14];
    const float* b4_ih = (const float*)d_in[15];
    const float* b4_hh = (const float*)d_in[16];

    float* out = (float*)d_out;

    // ws: flags[48] ints (poison 0xAAAAAAAA < 0 => "not ready"), then f16
    // panels h1 [T,B,128], h2 [T,B,32], h3 [T,B,128]
    int* flags = (int*)d_ws;
    f16* h1 = (f16*)((char*)d_ws + 256);
    f16* h2 = h1 + (size_t)T_STEPS * BATCH * 128;
    f16* h3 = h2 + (size_t)T_STEPS * BATCH * 32;

    lstm_fused<<<44, 512, 0, stream>>>(X,
        w1_ih, w1_hh, b1_ih, b1_hh, w2_ih, w2_hh, b2_ih, b2_hh,
        w3_ih, w3_hh, b3_ih, b3_hh, w4_ih, w4_hh, b4_ih, b4_hh,
        h1, h2, h3, flags, out);
}